// Round 13
// baseline (597.516 us; speedup 1.0000x reference)
//
#include <hip/hip_runtime.h>

// Problem constants (from reference): N=512, OBS=32, H=128, M=128, L=3
#define NA 512
#define NOBS 32
#define NH 128

typedef const float* fp32p;
typedef __attribute__((ext_vector_type(8))) short bf16x8;
typedef __attribute__((ext_vector_type(4))) float f32x4;

// fp32 -> bf16 (RNE) bit pattern
__device__ __forceinline__ short f2bf(float f) {
    union { float f; unsigned u; } v; v.f = f;
    unsigned r = v.u + 0x7fffu + ((v.u >> 16) & 1u);
    return (short)(r >> 16);
}

__device__ __forceinline__ bf16x8 wfrag_f4(const float* p) {  // 16B-aligned
    float4 u = *(const float4*)p;
    float4 v = *(const float4*)(p + 4);
    bf16x8 f;
    f[0] = f2bf(u.x); f[1] = f2bf(u.y); f[2] = f2bf(u.z); f[3] = f2bf(u.w);
    f[4] = f2bf(v.x); f[5] = f2bf(v.y); f[6] = f2bf(v.z); f[7] = f2bf(v.w);
    return f;
}

#define HSTR 136   // LDS row stride (shorts) for 128-wide bf16 tiles

// ---- software grid barrier -------------------------------------------------
// Safe without cooperative launch because ALL 512 blocks are co-resident by
// construction: LDS ~44.7KB -> 3 blocks/CU capacity (768 slots >= 512),
// VGPR ~60 -> no wave cap. Release: all threads __threadfence (drains CU +
// L2 writeback at agent scope) before arrival; acquire: agent-scope atomic
// loads (L1/L2 invalidate) before touching cross-block data.
__device__ __forceinline__ void gsync(unsigned* cnt, int s) {
    __threadfence();          // release: make this block's B writes visible
    __syncthreads();
    if (threadIdx.x == 0) {
        atomicAdd(&cnt[s], 1u);
        while (__hip_atomic_load(&cnt[s], __ATOMIC_RELAXED,
                                 __HIP_MEMORY_SCOPE_AGENT) < (unsigned)NA) {
            __builtin_amdgcn_s_sleep(2);
        }
    }
    __syncthreads();
    // acquire per thread: order subsequent normal loads after the barrier
    (void)__hip_atomic_load(&cnt[s], __ATOMIC_ACQUIRE, __HIP_MEMORY_SCOPE_AGENT);
}

__global__ void init_kernel(unsigned* cnt) {
    if (threadIdx.x < 8) cnt[threadIdx.x] = 0u;
}

// ---------------- single kernel: encoder + 3 x (msg + upd + ab) ------------
// Block i owns agent i end-to-end (R9 dataflow, R8 msg core, 64-row chunks).
// z / A_i / dist live in LDS; B is the only cross-block array (global,
// ping-pong, gsync between producer and consumer phases).
__global__ __launch_bounds__(512) void gnn_kernel(
    fp32p obs, fp32p pos,
    fp32p eW1, fp32p eb1, fp32p eW2, fp32p eb2, fp32p eW3, fp32p eb3,
    fp32p mW1, fp32p mb1, fp32p mW2, fp32p mb2, fp32p mW3, fp32p mb3,
    fp32p uW1, fp32p ub1, fp32p uW2, fp32p ub2, fp32p uW3, fp32p ub3,
    float* __restrict__ out, float* __restrict__ B0, float* __restrict__ B1,
    unsigned* __restrict__ cnt) {
    const int i = blockIdx.x;
    const int t = threadIdx.x;
    const int lane = t & 63;
    const int w = t >> 6;
    const int q = lane >> 4;
    const int c = lane & 15;
    const int ncol = w * 16 + c;
    const int nn = t >> 2;   // GEMV output row
    const int ks = t & 3;    // GEMV k-segment

    __shared__ short h1s[64 * HSTR];   // 17408 B
    __shared__ short h2s[64 * HSTR];   // 17408 B
    __shared__ float distrow[NA];      // persists across layers
    __shared__ float amrow[NH];
    __shared__ float wdsr[NH];
    __shared__ float arow_s[NH];       // raw A_i for current layer
    __shared__ float xs2[2 * NH];      // [z_i | msum_i]
    __shared__ float part[4 * NH];
    __shared__ float part2[4 * NH];
    __shared__ float hx[NH], hy[NH];
    __shared__ float xs0[NOBS];

    // ---------------- phase 0: dist row + encoder + layer-0 ab --------------
    {
        const float2 pi = *(const float2*)&pos[2 * i];
        const float2 pj = *(const float2*)&pos[2 * t];
        const float dx = pi.x - pj.x, dy = pi.y - pj.y;
        const float s = dx * dx + dy * dy;
        distrow[t] = (t == i) ? 0.0f : sqrtf(s);
    }
    if (t < NOBS) xs0[t] = obs[(size_t)i * NOBS + t];
    __syncthreads();
    // enc L1: K=32 (8 k per lane)
    {
        const float* wr = eW1 + (size_t)nn * NOBS + ks * 8;
        const float4 w0 = *(const float4*)wr;
        const float4 w1 = *(const float4*)(wr + 4);
        const float4 x0 = *(const float4*)&xs0[ks * 8];
        const float4 x1 = *(const float4*)&xs0[ks * 8 + 4];
        part[ks * NH + nn] = w0.x * x0.x + w0.y * x0.y + w0.z * x0.z + w0.w * x0.w +
                             w1.x * x1.x + w1.y * x1.y + w1.z * x1.z + w1.w * x1.w;
    }
    __syncthreads();
    if (t < NH)
        hx[t] = fmaxf(eb1[t] + part[t] + part[NH + t] + part[2 * NH + t] + part[3 * NH + t], 0.f);
    __syncthreads();
    // enc L2: K=128
    {
        const float* wr = eW2 + (size_t)nn * NH + ks * 4;
        float p = 0.f;
        #pragma unroll
        for (int it = 0; it < 8; ++it) {
            const float4 wv = *(const float4*)(wr + it * 16);
            const float4 xv = *(const float4*)&hx[it * 16 + ks * 4];
            p += wv.x * xv.x + wv.y * xv.y + wv.z * xv.z + wv.w * xv.w;
        }
        part[ks * NH + nn] = p;
    }
    __syncthreads();
    if (t < NH)
        hy[t] = fmaxf(eb2[t] + part[t] + part[NH + t] + part[2 * NH + t] + part[3 * NH + t], 0.f);
    __syncthreads();
    // enc L3: K=128, no relu -> z into xs2[0..127]
    {
        const float* wr = eW3 + (size_t)nn * NH + ks * 4;
        float p = 0.f;
        #pragma unroll
        for (int it = 0; it < 8; ++it) {
            const float4 wv = *(const float4*)(wr + it * 16);
            const float4 xv = *(const float4*)&hy[it * 16 + ks * 4];
            p += wv.x * xv.x + wv.y * xv.y + wv.z * xv.z + wv.w * xv.w;
        }
        part[ks * NH + nn] = p;
    }
    __syncthreads();
    if (t < NH)
        xs2[t] = eb3[t] + part[t] + part[NH + t] + part[2 * NH + t] + part[3 * NH + t];
    __syncthreads();
    // ab layer 0 from z
    {
        const float* pr = mW1 + (size_t)nn * 257;
        float pa = 0.f, pb = 0.f;
        #pragma unroll
        for (int it = 0; it < 8; ++it) {
            #pragma unroll
            for (int j = 0; j < 4; ++j) {
                const int k = it * 16 + ks * 4 + j;
                const float x = xs2[k];
                pa += x * pr[k];
                pb += x * pr[NH + k];
            }
        }
        part[ks * NH + nn] = pa;
        part2[ks * NH + nn] = pb;
    }
    __syncthreads();
    if (t < NH) {
        arow_s[t] = part[t] + part[NH + t] + part[2 * NH + t] + part[3 * NH + t];
        B0[(size_t)i * NH + t] = part2[t] + part2[NH + t] + part2[2 * NH + t] + part2[3 * NH + t];
    }
    gsync(cnt, 0);

    // ---------------- layers ----------------
    for (int l = 0; l < 3; ++l) {
        const float* Bc = (l == 1) ? B1 : B0;   // l0:B0, l1:B1, l2:B0
        float* Bn = (l == 0) ? B1 : B0;
        fp32p W1l = mW1 + (size_t)l * 128 * 257;
        fp32p b1l = mb1 + l * 128;
        fp32p W2l = mW2 + (size_t)l * 128 * 128;
        fp32p b2l = mb2 + l * 128;
        fp32p W3l = mW3 + (size_t)l * 128 * 128;
        fp32p b3l = mb3 + l * 128;
        fp32p uW1l = uW1 + (size_t)l * 256 * 128;
        fp32p ub1l = ub1 + l * 128;
        fp32p uW2l = uW2 + (size_t)l * 128 * 128;
        fp32p ub2l = ub2 + l * 128;
        fp32p uW3l = uW3 + (size_t)l * 128 * 128;
        fp32p ub3l = ub3 + l * 128;

        if (t < NH) {
            amrow[t] = arow_s[t] + b1l[t];
            wdsr[t]  = W1l[t * 257 + 256];
        }
        // register-resident weight fragments (one 16-col n-tile per wave)
        bf16x8 w2f[4], w3f[4];
        {
            const float* w2r = W2l + (size_t)ncol * NH + q * 8;
            const float* w3r = W3l + (size_t)ncol * NH + q * 8;
            #pragma unroll
            for (int kb = 0; kb < 4; ++kb) {
                w2f[kb] = wfrag_f4(w2r + kb * 32);
                w3f[kb] = wfrag_f4(w3r + kb * 32);
            }
        }
        const float b2n = b2l[ncol];
        const float b3n = b3l[ncol];

        const int m2 = lane * 2;
        float psum = 0.0f;

        for (int c8 = 0; c8 < 8; ++c8) {
            const int j0 = c8 * 64;
            __syncthreads();

            // ---- build h1 chunk (64 x 128) as bf16 ----
            {
                const float am0 = amrow[m2],     am1 = amrow[m2 + 1];
                const float wd0 = wdsr[m2],      wd1 = wdsr[m2 + 1];
                #pragma unroll
                for (int rr = 0; rr < 8; ++rr) {
                    const int row = rr * 8 + w;
                    const int jg  = j0 + row;
                    const float2 bv = *(const float2*)&Bc[(size_t)jg * NH + m2];
                    const float d = distrow[jg];
                    const float v0 = fmaxf(am0 + bv.x + d * wd0, 0.0f);
                    const float v1 = fmaxf(am1 + bv.y + d * wd1, 0.0f);
                    const unsigned p = (unsigned)(unsigned short)f2bf(v0) |
                                       ((unsigned)(unsigned short)f2bf(v1) << 16);
                    *(unsigned*)&h1s[row * HSTR + m2] = p;
                }
            }
            __syncthreads();

            // ---- GEMM1: h2 = relu(h1 @ W2^T + b2) ----
            #pragma unroll
            for (int jt = 0; jt < 4; ++jt) {
                f32x4 acc = {0.f, 0.f, 0.f, 0.f};
                const short* arow = &h1s[(jt * 16 + c) * HSTR + q * 8];
                #pragma unroll
                for (int kb = 0; kb < 4; ++kb) {
                    bf16x8 a = *(const bf16x8*)(arow + kb * 32);
                    acc = __builtin_amdgcn_mfma_f32_16x16x32_bf16(a, w2f[kb], acc, 0, 0, 0);
                }
                #pragma unroll
                for (int r = 0; r < 4; ++r) {
                    const int row = jt * 16 + q * 4 + r;
                    h2s[row * HSTR + ncol] = f2bf(fmaxf(acc[r] + b2n, 0.0f));
                }
            }
            __syncthreads();

            // ---- GEMM2: diag-masked column sum of h2 @ W3^T + b3 ----
            #pragma unroll
            for (int jt = 0; jt < 4; ++jt) {
                f32x4 acc = {0.f, 0.f, 0.f, 0.f};
                const short* arow = &h2s[(jt * 16 + c) * HSTR + q * 8];
                #pragma unroll
                for (int kb = 0; kb < 4; ++kb) {
                    bf16x8 a = *(const bf16x8*)(arow + kb * 32);
                    acc = __builtin_amdgcn_mfma_f32_16x16x32_bf16(a, w3f[kb], acc, 0, 0, 0);
                }
                #pragma unroll
                for (int r = 0; r < 4; ++r) {
                    const int jg = j0 + jt * 16 + q * 4 + r;
                    if (jg != i) psum += acc[r] + b3n;
                }
            }
        }

        // ---- msum: reduce over quads (same ncol), into xs2 hi half ----
        psum += __shfl_xor(psum, 16, 64);
        psum += __shfl_xor(psum, 32, 64);
        if (lane < 16) xs2[NH + ncol] = psum;
        __syncthreads();

        // ---- tail: update MLP (fp32 GEMV, 4 lanes per output row) ----
        // L1: K=256
        {
            const float* wr = uW1l + (size_t)nn * 256 + ks * 4;
            float p = 0.f;
            #pragma unroll
            for (int it = 0; it < 16; ++it) {
                const float4 wv = *(const float4*)(wr + it * 16);
                const float4 xv = *(const float4*)&xs2[it * 16 + ks * 4];
                p += wv.x * xv.x + wv.y * xv.y + wv.z * xv.z + wv.w * xv.w;
            }
            part[ks * NH + nn] = p;
        }
        __syncthreads();
        if (t < NH)
            hx[t] = fmaxf(ub1l[t] + part[t] + part[NH + t] + part[2 * NH + t] + part[3 * NH + t], 0.f);
        __syncthreads();
        // L2: K=128
        {
            const float* wr = uW2l + (size_t)nn * NH + ks * 4;
            float p = 0.f;
            #pragma unroll
            for (int it = 0; it < 8; ++it) {
                const float4 wv = *(const float4*)(wr + it * 16);
                const float4 xv = *(const float4*)&hx[it * 16 + ks * 4];
                p += wv.x * xv.x + wv.y * xv.y + wv.z * xv.z + wv.w * xv.w;
            }
            part[ks * NH + nn] = p;
        }
        __syncthreads();
        if (t < NH)
            hy[t] = fmaxf(ub2l[t] + part[t] + part[NH + t] + part[2 * NH + t] + part[3 * NH + t], 0.f);
        __syncthreads();
        // L3: K=128, no relu
        {
            const float* wr = uW3l + (size_t)nn * NH + ks * 4;
            float p = 0.f;
            #pragma unroll
            for (int it = 0; it < 8; ++it) {
                const float4 wv = *(const float4*)(wr + it * 16);
                const float4 xv = *(const float4*)&hy[it * 16 + ks * 4];
                p += wv.x * xv.x + wv.y * xv.y + wv.z * xv.z + wv.w * xv.w;
            }
            part[ks * NH + nn] = p;
        }
        __syncthreads();
        if (t < NH) {
            const float v = ub3l[t] + part[t] + part[NH + t] + part[2 * NH + t] + part[3 * NH + t];
            if (l == 2) out[(size_t)i * NH + t] = v;
            hx[t] = v;   // new z
        }
        if (l < 2) {
            __syncthreads();
            // ab for next layer from new z (hx)
            {
                const float* pr = mW1 + (size_t)(l + 1) * 128 * 257 + (size_t)nn * 257;
                float pa = 0.f, pb = 0.f;
                #pragma unroll
                for (int it = 0; it < 8; ++it) {
                    #pragma unroll
                    for (int j = 0; j < 4; ++j) {
                        const int k = it * 16 + ks * 4 + j;
                        const float x = hx[k];
                        pa += x * pr[k];
                        pb += x * pr[NH + k];
                    }
                }
                part[ks * NH + nn] = pa;
                part2[ks * NH + nn] = pb;
            }
            __syncthreads();
            if (t < NH) {
                arow_s[t] = part[t] + part[NH + t] + part[2 * NH + t] + part[3 * NH + t];
                Bn[(size_t)i * NH + t] = part2[t] + part2[NH + t] + part2[2 * NH + t] + part2[3 * NH + t];
                xs2[t] = hx[t];   // z for next layer's tail
            }
            gsync(cnt, 1 + l);
        }
    }
}

// ---------------------------------------------------------------- host ------
extern "C" void kernel_launch(void* const* d_in, const int* in_sizes, int n_in,
                              void* d_out, int out_size, void* d_ws, size_t ws_size,
                              hipStream_t stream) {
    fp32p obs   = (fp32p)d_in[0];
    fp32p pos   = (fp32p)d_in[1];
    fp32p encW1 = (fp32p)d_in[2];  fp32p encb1 = (fp32p)d_in[3];
    fp32p encW2 = (fp32p)d_in[4];  fp32p encb2 = (fp32p)d_in[5];
    fp32p encW3 = (fp32p)d_in[6];  fp32p encb3 = (fp32p)d_in[7];
    fp32p msgW1 = (fp32p)d_in[8];  fp32p msgb1 = (fp32p)d_in[9];
    fp32p msgW2 = (fp32p)d_in[10]; fp32p msgb2 = (fp32p)d_in[11];
    fp32p msgW3 = (fp32p)d_in[12]; fp32p msgb3 = (fp32p)d_in[13];
    fp32p updW1 = (fp32p)d_in[14]; fp32p updb1 = (fp32p)d_in[15];
    fp32p updW2 = (fp32p)d_in[16]; fp32p updb2 = (fp32p)d_in[17];
    fp32p updW3 = (fp32p)d_in[18]; fp32p updb3 = (fp32p)d_in[19];

    float* ws = (float*)d_ws;
    float* B0 = ws;
    float* B1 = B0 + NA * NH;
    unsigned* cnt = (unsigned*)(B1 + NA * NH);

    init_kernel<<<1, 64, 0, stream>>>(cnt);
    gnn_kernel<<<NA, 512, 0, stream>>>(
        obs, pos,
        encW1, encb1, encW2, encb2, encW3, encb3,
        msgW1, msgb1, msgW2, msgb2, msgW3, msgb3,
        updW1, updb1, updW2, updb2, updW3, updb3,
        (float*)d_out, B0, B1, cnt);
}

// Round 14
// 372.410 us; speedup vs baseline: 1.6045x; 1.6045x over previous
//
#include <hip/hip_runtime.h>

// Problem constants (from reference): N=512, OBS=32, H=128, M=128, L=3
#define NA 512
#define NOBS 32
#define NH 128

typedef const float* fp32p;
typedef __attribute__((ext_vector_type(8))) short bf16x8;
typedef __attribute__((ext_vector_type(4))) float f32x4;

// fp32 -> bf16 (RNE) bit pattern
__device__ __forceinline__ short f2bf(float f) {
    union { float f; unsigned u; } v; v.f = f;
    unsigned r = v.u + 0x7fffu + ((v.u >> 16) & 1u);
    return (short)(r >> 16);
}

__device__ __forceinline__ bf16x8 wfrag_f4(const float* p) {  // 16B-aligned
    float4 u = *(const float4*)p;
    float4 v = *(const float4*)(p + 4);
    bf16x8 f;
    f[0] = f2bf(u.x); f[1] = f2bf(u.y); f[2] = f2bf(u.z); f[3] = f2bf(u.w);
    f[4] = f2bf(v.x); f[5] = f2bf(v.y); f[6] = f2bf(v.z); f[7] = f2bf(v.w);
    return f;
}

#define HSTR 136   // LDS row stride (shorts) for 128-wide bf16 tiles

// ---- software grid barrier, SINGLE-THREAD fencing --------------------------
// R13's version ran the agent fences in all 512 threads -> ~260K L2
// writeback/invalidate ops per barrier, thrashing every XCD L2 (85% idle).
// Caches are shared at the right granularity (block = 1 CU = shared L1,
// 1 XCD = shared L2) and __syncthreads drains each wave's vmcnt (stores
// reach L2 before s_barrier). So thread 0 alone does: release fence (one
// wbl2), arrival atomic, spin (relaxed), acquire fence (one inv). 512x
// fewer cache-maintenance ops; no mid-compute L2 thrash.
// Co-residency for deadlock-freedom: LDS ~45KB -> 3 blocks/CU capacity,
// VGPR ~64 -> 512 blocks all resident on 256 CUs.
__device__ __forceinline__ void gsync(unsigned* cnt, int s) {
    __syncthreads();   // all waves' stores drained to L2 (vmcnt(0) before barrier)
    if (threadIdx.x == 0) {
        __builtin_amdgcn_fence(__ATOMIC_RELEASE, "agent");  // push L2 -> coherence
        atomicAdd(&cnt[s], 1u);
        while (__hip_atomic_load(&cnt[s], __ATOMIC_RELAXED,
                                 __HIP_MEMORY_SCOPE_AGENT) < (unsigned)NA) {
            __builtin_amdgcn_s_sleep(8);
        }
        __builtin_amdgcn_fence(__ATOMIC_ACQUIRE, "agent");  // inv L1/L2 once
    }
    __syncthreads();
}

__global__ void init_kernel(unsigned* cnt) {
    if (threadIdx.x < 8) cnt[threadIdx.x] = 0u;
}

// ---------------- single kernel: encoder + 3 x (msg + upd + ab) ------------
// Block i owns agent i end-to-end (R9 dataflow, R8 msg core, 64-row chunks).
// z / A_i / dist live in LDS; B is the only cross-block array (global,
// ping-pong, gsync between producer and consumer phases).
__global__ __launch_bounds__(512) void gnn_kernel(
    fp32p obs, fp32p pos,
    fp32p eW1, fp32p eb1, fp32p eW2, fp32p eb2, fp32p eW3, fp32p eb3,
    fp32p mW1, fp32p mb1, fp32p mW2, fp32p mb2, fp32p mW3, fp32p mb3,
    fp32p uW1, fp32p ub1, fp32p uW2, fp32p ub2, fp32p uW3, fp32p ub3,
    float* __restrict__ out, float* __restrict__ B0, float* __restrict__ B1,
    unsigned* __restrict__ cnt) {
    const int i = blockIdx.x;
    const int t = threadIdx.x;
    const int lane = t & 63;
    const int w = t >> 6;
    const int q = lane >> 4;
    const int c = lane & 15;
    const int ncol = w * 16 + c;
    const int nn = t >> 2;   // GEMV output row
    const int ks = t & 3;    // GEMV k-segment

    __shared__ short h1s[64 * HSTR];   // 17408 B
    __shared__ short h2s[64 * HSTR];   // 17408 B
    __shared__ float distrow[NA];      // persists across layers
    __shared__ float amrow[NH];
    __shared__ float wdsr[NH];
    __shared__ float arow_s[NH];       // raw A_i for current layer
    __shared__ float xs2[2 * NH];      // [z_i | msum_i]
    __shared__ float part[4 * NH];
    __shared__ float part2[4 * NH];
    __shared__ float hx[NH], hy[NH];
    __shared__ float xs0[NOBS];

    // ---------------- phase 0: dist row + encoder + layer-0 ab --------------
    {
        const float2 pi = *(const float2*)&pos[2 * i];
        const float2 pj = *(const float2*)&pos[2 * t];
        const float dx = pi.x - pj.x, dy = pi.y - pj.y;
        const float s = dx * dx + dy * dy;
        distrow[t] = (t == i) ? 0.0f : sqrtf(s);
    }
    if (t < NOBS) xs0[t] = obs[(size_t)i * NOBS + t];
    __syncthreads();
    // enc L1: K=32 (8 k per lane)
    {
        const float* wr = eW1 + (size_t)nn * NOBS + ks * 8;
        const float4 w0 = *(const float4*)wr;
        const float4 w1 = *(const float4*)(wr + 4);
        const float4 x0 = *(const float4*)&xs0[ks * 8];
        const float4 x1 = *(const float4*)&xs0[ks * 8 + 4];
        part[ks * NH + nn] = w0.x * x0.x + w0.y * x0.y + w0.z * x0.z + w0.w * x0.w +
                             w1.x * x1.x + w1.y * x1.y + w1.z * x1.z + w1.w * x1.w;
    }
    __syncthreads();
    if (t < NH)
        hx[t] = fmaxf(eb1[t] + part[t] + part[NH + t] + part[2 * NH + t] + part[3 * NH + t], 0.f);
    __syncthreads();
    // enc L2: K=128
    {
        const float* wr = eW2 + (size_t)nn * NH + ks * 4;
        float p = 0.f;
        #pragma unroll
        for (int it = 0; it < 8; ++it) {
            const float4 wv = *(const float4*)(wr + it * 16);
            const float4 xv = *(const float4*)&hx[it * 16 + ks * 4];
            p += wv.x * xv.x + wv.y * xv.y + wv.z * xv.z + wv.w * xv.w;
        }
        part[ks * NH + nn] = p;
    }
    __syncthreads();
    if (t < NH)
        hy[t] = fmaxf(eb2[t] + part[t] + part[NH + t] + part[2 * NH + t] + part[3 * NH + t], 0.f);
    __syncthreads();
    // enc L3: K=128, no relu -> z into xs2[0..127]
    {
        const float* wr = eW3 + (size_t)nn * NH + ks * 4;
        float p = 0.f;
        #pragma unroll
        for (int it = 0; it < 8; ++it) {
            const float4 wv = *(const float4*)(wr + it * 16);
            const float4 xv = *(const float4*)&hy[it * 16 + ks * 4];
            p += wv.x * xv.x + wv.y * xv.y + wv.z * xv.z + wv.w * xv.w;
        }
        part[ks * NH + nn] = p;
    }
    __syncthreads();
    if (t < NH)
        xs2[t] = eb3[t] + part[t] + part[NH + t] + part[2 * NH + t] + part[3 * NH + t];
    __syncthreads();
    // ab layer 0 from z
    {
        const float* pr = mW1 + (size_t)nn * 257;
        float pa = 0.f, pb = 0.f;
        #pragma unroll
        for (int it = 0; it < 8; ++it) {
            #pragma unroll
            for (int j = 0; j < 4; ++j) {
                const int k = it * 16 + ks * 4 + j;
                const float x = xs2[k];
                pa += x * pr[k];
                pb += x * pr[NH + k];
            }
        }
        part[ks * NH + nn] = pa;
        part2[ks * NH + nn] = pb;
    }
    __syncthreads();
    if (t < NH) {
        arow_s[t] = part[t] + part[NH + t] + part[2 * NH + t] + part[3 * NH + t];
        B0[(size_t)i * NH + t] = part2[t] + part2[NH + t] + part2[2 * NH + t] + part2[3 * NH + t];
    }
    gsync(cnt, 0);

    // ---------------- layers ----------------
    for (int l = 0; l < 3; ++l) {
        const float* Bc = (l == 1) ? B1 : B0;   // l0:B0, l1:B1, l2:B0
        float* Bn = (l == 0) ? B1 : B0;
        fp32p W1l = mW1 + (size_t)l * 128 * 257;
        fp32p b1l = mb1 + l * 128;
        fp32p W2l = mW2 + (size_t)l * 128 * 128;
        fp32p b2l = mb2 + l * 128;
        fp32p W3l = mW3 + (size_t)l * 128 * 128;
        fp32p b3l = mb3 + l * 128;
        fp32p uW1l = uW1 + (size_t)l * 256 * 128;
        fp32p ub1l = ub1 + l * 128;
        fp32p uW2l = uW2 + (size_t)l * 128 * 128;
        fp32p ub2l = ub2 + l * 128;
        fp32p uW3l = uW3 + (size_t)l * 128 * 128;
        fp32p ub3l = ub3 + l * 128;

        if (t < NH) {
            amrow[t] = arow_s[t] + b1l[t];
            wdsr[t]  = W1l[t * 257 + 256];
        }
        // register-resident weight fragments (one 16-col n-tile per wave)
        bf16x8 w2f[4], w3f[4];
        {
            const float* w2r = W2l + (size_t)ncol * NH + q * 8;
            const float* w3r = W3l + (size_t)ncol * NH + q * 8;
            #pragma unroll
            for (int kb = 0; kb < 4; ++kb) {
                w2f[kb] = wfrag_f4(w2r + kb * 32);
                w3f[kb] = wfrag_f4(w3r + kb * 32);
            }
        }
        const float b2n = b2l[ncol];
        const float b3n = b3l[ncol];

        const int m2 = lane * 2;
        float psum = 0.0f;

        for (int c8 = 0; c8 < 8; ++c8) {
            const int j0 = c8 * 64;
            __syncthreads();

            // ---- build h1 chunk (64 x 128) as bf16 ----
            {
                const float am0 = amrow[m2],     am1 = amrow[m2 + 1];
                const float wd0 = wdsr[m2],      wd1 = wdsr[m2 + 1];
                #pragma unroll
                for (int rr = 0; rr < 8; ++rr) {
                    const int row = rr * 8 + w;
                    const int jg  = j0 + row;
                    const float2 bv = *(const float2*)&Bc[(size_t)jg * NH + m2];
                    const float d = distrow[jg];
                    const float v0 = fmaxf(am0 + bv.x + d * wd0, 0.0f);
                    const float v1 = fmaxf(am1 + bv.y + d * wd1, 0.0f);
                    const unsigned p = (unsigned)(unsigned short)f2bf(v0) |
                                       ((unsigned)(unsigned short)f2bf(v1) << 16);
                    *(unsigned*)&h1s[row * HSTR + m2] = p;
                }
            }
            __syncthreads();

            // ---- GEMM1: h2 = relu(h1 @ W2^T + b2) ----
            #pragma unroll
            for (int jt = 0; jt < 4; ++jt) {
                f32x4 acc = {0.f, 0.f, 0.f, 0.f};
                const short* arow = &h1s[(jt * 16 + c) * HSTR + q * 8];
                #pragma unroll
                for (int kb = 0; kb < 4; ++kb) {
                    bf16x8 a = *(const bf16x8*)(arow + kb * 32);
                    acc = __builtin_amdgcn_mfma_f32_16x16x32_bf16(a, w2f[kb], acc, 0, 0, 0);
                }
                #pragma unroll
                for (int r = 0; r < 4; ++r) {
                    const int row = jt * 16 + q * 4 + r;
                    h2s[row * HSTR + ncol] = f2bf(fmaxf(acc[r] + b2n, 0.0f));
                }
            }
            __syncthreads();

            // ---- GEMM2: diag-masked column sum of h2 @ W3^T + b3 ----
            #pragma unroll
            for (int jt = 0; jt < 4; ++jt) {
                f32x4 acc = {0.f, 0.f, 0.f, 0.f};
                const short* arow = &h2s[(jt * 16 + c) * HSTR + q * 8];
                #pragma unroll
                for (int kb = 0; kb < 4; ++kb) {
                    bf16x8 a = *(const bf16x8*)(arow + kb * 32);
                    acc = __builtin_amdgcn_mfma_f32_16x16x32_bf16(a, w3f[kb], acc, 0, 0, 0);
                }
                #pragma unroll
                for (int r = 0; r < 4; ++r) {
                    const int jg = j0 + jt * 16 + q * 4 + r;
                    if (jg != i) psum += acc[r] + b3n;
                }
            }
        }

        // ---- msum: reduce over quads (same ncol), into xs2 hi half ----
        psum += __shfl_xor(psum, 16, 64);
        psum += __shfl_xor(psum, 32, 64);
        if (lane < 16) xs2[NH + ncol] = psum;
        __syncthreads();

        // ---- tail: update MLP (fp32 GEMV, 4 lanes per output row) ----
        // L1: K=256
        {
            const float* wr = uW1l + (size_t)nn * 256 + ks * 4;
            float p = 0.f;
            #pragma unroll
            for (int it = 0; it < 16; ++it) {
                const float4 wv = *(const float4*)(wr + it * 16);
                const float4 xv = *(const float4*)&xs2[it * 16 + ks * 4];
                p += wv.x * xv.x + wv.y * xv.y + wv.z * xv.z + wv.w * xv.w;
            }
            part[ks * NH + nn] = p;
        }
        __syncthreads();
        if (t < NH)
            hx[t] = fmaxf(ub1l[t] + part[t] + part[NH + t] + part[2 * NH + t] + part[3 * NH + t], 0.f);
        __syncthreads();
        // L2: K=128
        {
            const float* wr = uW2l + (size_t)nn * NH + ks * 4;
            float p = 0.f;
            #pragma unroll
            for (int it = 0; it < 8; ++it) {
                const float4 wv = *(const float4*)(wr + it * 16);
                const float4 xv = *(const float4*)&hx[it * 16 + ks * 4];
                p += wv.x * xv.x + wv.y * xv.y + wv.z * xv.z + wv.w * xv.w;
            }
            part[ks * NH + nn] = p;
        }
        __syncthreads();
        if (t < NH)
            hy[t] = fmaxf(ub2l[t] + part[t] + part[NH + t] + part[2 * NH + t] + part[3 * NH + t], 0.f);
        __syncthreads();
        // L3: K=128, no relu
        {
            const float* wr = uW3l + (size_t)nn * NH + ks * 4;
            float p = 0.f;
            #pragma unroll
            for (int it = 0; it < 8; ++it) {
                const float4 wv = *(const float4*)(wr + it * 16);
                const float4 xv = *(const float4*)&hy[it * 16 + ks * 4];
                p += wv.x * xv.x + wv.y * xv.y + wv.z * xv.z + wv.w * xv.w;
            }
            part[ks * NH + nn] = p;
        }
        __syncthreads();
        if (t < NH) {
            const float v = ub3l[t] + part[t] + part[NH + t] + part[2 * NH + t] + part[3 * NH + t];
            if (l == 2) out[(size_t)i * NH + t] = v;
            hx[t] = v;   // new z
        }
        if (l < 2) {
            __syncthreads();
            // ab for next layer from new z (hx)
            {
                const float* pr = mW1 + (size_t)(l + 1) * 128 * 257 + (size_t)nn * 257;
                float pa = 0.f, pb = 0.f;
                #pragma unroll
                for (int it = 0; it < 8; ++it) {
                    #pragma unroll
                    for (int j = 0; j < 4; ++j) {
                        const int k = it * 16 + ks * 4 + j;
                        const float x = hx[k];
                        pa += x * pr[k];
                        pb += x * pr[NH + k];
                    }
                }
                part[ks * NH + nn] = pa;
                part2[ks * NH + nn] = pb;
            }
            __syncthreads();
            if (t < NH) {
                arow_s[t] = part[t] + part[NH + t] + part[2 * NH + t] + part[3 * NH + t];
                Bn[(size_t)i * NH + t] = part2[t] + part2[NH + t] + part2[2 * NH + t] + part2[3 * NH + t];
                xs2[t] = hx[t];   // z for next layer's tail
            }
            gsync(cnt, 1 + l);
        }
    }
}

// ---------------------------------------------------------------- host ------
extern "C" void kernel_launch(void* const* d_in, const int* in_sizes, int n_in,
                              void* d_out, int out_size, void* d_ws, size_t ws_size,
                              hipStream_t stream) {
    fp32p obs   = (fp32p)d_in[0];
    fp32p pos   = (fp32p)d_in[1];
    fp32p encW1 = (fp32p)d_in[2];  fp32p encb1 = (fp32p)d_in[3];
    fp32p encW2 = (fp32p)d_in[4];  fp32p encb2 = (fp32p)d_in[5];
    fp32p encW3 = (fp32p)d_in[6];  fp32p encb3 = (fp32p)d_in[7];
    fp32p msgW1 = (fp32p)d_in[8];  fp32p msgb1 = (fp32p)d_in[9];
    fp32p msgW2 = (fp32p)d_in[10]; fp32p msgb2 = (fp32p)d_in[11];
    fp32p msgW3 = (fp32p)d_in[12]; fp32p msgb3 = (fp32p)d_in[13];
    fp32p updW1 = (fp32p)d_in[14]; fp32p updb1 = (fp32p)d_in[15];
    fp32p updW2 = (fp32p)d_in[16]; fp32p updb2 = (fp32p)d_in[17];
    fp32p updW3 = (fp32p)d_in[18]; fp32p updb3 = (fp32p)d_in[19];

    float* ws = (float*)d_ws;
    float* B0 = ws;
    float* B1 = B0 + NA * NH;
    unsigned* cnt = (unsigned*)(B1 + NA * NH);

    init_kernel<<<1, 64, 0, stream>>>(cnt);
    gnn_kernel<<<NA, 512, 0, stream>>>(
        obs, pos,
        encW1, encb1, encW2, encb2, encW3, encb3,
        msgW1, msgb1, msgW2, msgb2, msgW3, msgb3,
        updW1, updb1, updW2, updb2, updW3, updb3,
        (float*)d_out, B0, B1, cnt);
}

// Round 15
// 290.344 us; speedup vs baseline: 2.0580x; 1.2826x over previous
//
#include <hip/hip_runtime.h>

// Problem constants (from reference): N=512, OBS=32, H=128, M=128, L=3
#define NA 512
#define NOBS 32
#define NH 128

typedef const float* fp32p;
typedef __attribute__((ext_vector_type(8))) short bf16x8;
typedef __attribute__((ext_vector_type(4))) float f32x4;

// fp32 -> bf16 (RNE) bit pattern
__device__ __forceinline__ short f2bf(float f) {
    union { float f; unsigned u; } v; v.f = f;
    unsigned r = v.u + 0x7fffu + ((v.u >> 16) & 1u);
    return (short)(r >> 16);
}

__device__ __forceinline__ bf16x8 wfrag_f4(const float* p) {  // 16B-aligned
    float4 u = *(const float4*)p;
    float4 v = *(const float4*)(p + 4);
    bf16x8 f;
    f[0] = f2bf(u.x); f[1] = f2bf(u.y); f[2] = f2bf(u.z); f[3] = f2bf(u.w);
    f[4] = f2bf(v.x); f[5] = f2bf(v.y); f[6] = f2bf(v.z); f[7] = f2bf(v.w);
    return f;
}

#define HSTR 136   // LDS row stride (shorts) for 128-wide bf16 tiles

// ---- software grid barrier: sense-separated counter + flag -----------------
// R14 post-mortem: spinners polled the SAME line the arrival atomicAdds
// target -> ~2500 same-line probes/us queued at the coherence point, each
// arrival RMW serialized behind them => ~48us per barrier of pure idle.
// Fix: arrivals hit cnt[s] (own 128B line); the LAST arriver release-stores
// flag[s] (different 128B line); all others spin READ-ONLY on flag[s]
// (plain agent loads broadcast; no RMW serialization) with ~0.85us backoff.
// Single-thread fencing kept from R14 (all-thread fences thrashed L2, R13).
// Co-residency: LDS ~45KB -> 3 blocks/CU cap, VGPR ~64 -> all 512 resident.
#define CNT(s)  (sync_ws[(s) * 32])
#define FLAG(s) (sync_ws[512 + (s) * 32])
__device__ __forceinline__ void gsync(unsigned* sync_ws, int s) {
    __syncthreads();   // all waves' stores drained to L2 (vmcnt(0) before barrier)
    if (threadIdx.x == 0) {
        __builtin_amdgcn_fence(__ATOMIC_RELEASE, "agent");
        unsigned old = __hip_atomic_fetch_add(&CNT(s), 1u, __ATOMIC_RELAXED,
                                              __HIP_MEMORY_SCOPE_AGENT);
        if (old == (unsigned)(NA - 1)) {
            __hip_atomic_store(&FLAG(s), 1u, __ATOMIC_RELEASE,
                               __HIP_MEMORY_SCOPE_AGENT);
        } else {
            while (__hip_atomic_load(&FLAG(s), __ATOMIC_RELAXED,
                                     __HIP_MEMORY_SCOPE_AGENT) == 0u) {
                __builtin_amdgcn_s_sleep(32);
            }
        }
        __builtin_amdgcn_fence(__ATOMIC_ACQUIRE, "agent");
    }
    __syncthreads();
}

__global__ void init_kernel(unsigned* sync_ws) {
    sync_ws[threadIdx.x] = 0u;   // 1024 threads: cnt lines + flag lines
}

// ---------------- single kernel: encoder + 3 x (msg + upd + ab) ------------
// Block i owns agent i end-to-end (R9 dataflow, R8 msg core, 64-row chunks).
// z / A_i / dist live in LDS; B is the only cross-block array (global,
// ping-pong, gsync between producer and consumer phases).
__global__ __launch_bounds__(512) void gnn_kernel(
    fp32p obs, fp32p pos,
    fp32p eW1, fp32p eb1, fp32p eW2, fp32p eb2, fp32p eW3, fp32p eb3,
    fp32p mW1, fp32p mb1, fp32p mW2, fp32p mb2, fp32p mW3, fp32p mb3,
    fp32p uW1, fp32p ub1, fp32p uW2, fp32p ub2, fp32p uW3, fp32p ub3,
    float* __restrict__ out, float* __restrict__ B0, float* __restrict__ B1,
    unsigned* __restrict__ sync_ws) {
    const int i = blockIdx.x;
    const int t = threadIdx.x;
    const int lane = t & 63;
    const int w = t >> 6;
    const int q = lane >> 4;
    const int c = lane & 15;
    const int ncol = w * 16 + c;
    const int nn = t >> 2;   // GEMV output row
    const int ks = t & 3;    // GEMV k-segment

    __shared__ short h1s[64 * HSTR];   // 17408 B
    __shared__ short h2s[64 * HSTR];   // 17408 B
    __shared__ float distrow[NA];      // persists across layers
    __shared__ float amrow[NH];
    __shared__ float wdsr[NH];
    __shared__ float arow_s[NH];       // raw A_i for current layer
    __shared__ float xs2[2 * NH];      // [z_i | msum_i]
    __shared__ float part[4 * NH];
    __shared__ float part2[4 * NH];
    __shared__ float hx[NH], hy[NH];
    __shared__ float xs0[NOBS];

    // ---------------- phase 0: dist row + encoder + layer-0 ab --------------
    {
        const float2 pi = *(const float2*)&pos[2 * i];
        const float2 pj = *(const float2*)&pos[2 * t];
        const float dx = pi.x - pj.x, dy = pi.y - pj.y;
        const float s = dx * dx + dy * dy;
        distrow[t] = (t == i) ? 0.0f : sqrtf(s);
    }
    if (t < NOBS) xs0[t] = obs[(size_t)i * NOBS + t];
    __syncthreads();
    // enc L1: K=32 (8 k per lane)
    {
        const float* wr = eW1 + (size_t)nn * NOBS + ks * 8;
        const float4 w0 = *(const float4*)wr;
        const float4 w1 = *(const float4*)(wr + 4);
        const float4 x0 = *(const float4*)&xs0[ks * 8];
        const float4 x1 = *(const float4*)&xs0[ks * 8 + 4];
        part[ks * NH + nn] = w0.x * x0.x + w0.y * x0.y + w0.z * x0.z + w0.w * x0.w +
                             w1.x * x1.x + w1.y * x1.y + w1.z * x1.z + w1.w * x1.w;
    }
    __syncthreads();
    if (t < NH)
        hx[t] = fmaxf(eb1[t] + part[t] + part[NH + t] + part[2 * NH + t] + part[3 * NH + t], 0.f);
    __syncthreads();
    // enc L2: K=128
    {
        const float* wr = eW2 + (size_t)nn * NH + ks * 4;
        float p = 0.f;
        #pragma unroll
        for (int it = 0; it < 8; ++it) {
            const float4 wv = *(const float4*)(wr + it * 16);
            const float4 xv = *(const float4*)&hx[it * 16 + ks * 4];
            p += wv.x * xv.x + wv.y * xv.y + wv.z * xv.z + wv.w * xv.w;
        }
        part[ks * NH + nn] = p;
    }
    __syncthreads();
    if (t < NH)
        hy[t] = fmaxf(eb2[t] + part[t] + part[NH + t] + part[2 * NH + t] + part[3 * NH + t], 0.f);
    __syncthreads();
    // enc L3: K=128, no relu -> z into xs2[0..127]
    {
        const float* wr = eW3 + (size_t)nn * NH + ks * 4;
        float p = 0.f;
        #pragma unroll
        for (int it = 0; it < 8; ++it) {
            const float4 wv = *(const float4*)(wr + it * 16);
            const float4 xv = *(const float4*)&hy[it * 16 + ks * 4];
            p += wv.x * xv.x + wv.y * xv.y + wv.z * xv.z + wv.w * xv.w;
        }
        part[ks * NH + nn] = p;
    }
    __syncthreads();
    if (t < NH)
        xs2[t] = eb3[t] + part[t] + part[NH + t] + part[2 * NH + t] + part[3 * NH + t];
    __syncthreads();
    // ab layer 0 from z
    {
        const float* pr = mW1 + (size_t)nn * 257;
        float pa = 0.f, pb = 0.f;
        #pragma unroll
        for (int it = 0; it < 8; ++it) {
            #pragma unroll
            for (int j = 0; j < 4; ++j) {
                const int k = it * 16 + ks * 4 + j;
                const float x = xs2[k];
                pa += x * pr[k];
                pb += x * pr[NH + k];
            }
        }
        part[ks * NH + nn] = pa;
        part2[ks * NH + nn] = pb;
    }
    __syncthreads();
    if (t < NH) {
        arow_s[t] = part[t] + part[NH + t] + part[2 * NH + t] + part[3 * NH + t];
        B0[(size_t)i * NH + t] = part2[t] + part2[NH + t] + part2[2 * NH + t] + part2[3 * NH + t];
    }
    gsync(sync_ws, 0);

    // ---------------- layers ----------------
    for (int l = 0; l < 3; ++l) {
        const float* Bc = (l == 1) ? B1 : B0;   // l0:B0, l1:B1, l2:B0
        float* Bn = (l == 0) ? B1 : B0;
        fp32p W1l = mW1 + (size_t)l * 128 * 257;
        fp32p b1l = mb1 + l * 128;
        fp32p W2l = mW2 + (size_t)l * 128 * 128;
        fp32p b2l = mb2 + l * 128;
        fp32p W3l = mW3 + (size_t)l * 128 * 128;
        fp32p b3l = mb3 + l * 128;
        fp32p uW1l = uW1 + (size_t)l * 256 * 128;
        fp32p ub1l = ub1 + l * 128;
        fp32p uW2l = uW2 + (size_t)l * 128 * 128;
        fp32p ub2l = ub2 + l * 128;
        fp32p uW3l = uW3 + (size_t)l * 128 * 128;
        fp32p ub3l = ub3 + l * 128;

        if (t < NH) {
            amrow[t] = arow_s[t] + b1l[t];
            wdsr[t]  = W1l[t * 257 + 256];
        }
        // register-resident weight fragments (one 16-col n-tile per wave)
        bf16x8 w2f[4], w3f[4];
        {
            const float* w2r = W2l + (size_t)ncol * NH + q * 8;
            const float* w3r = W3l + (size_t)ncol * NH + q * 8;
            #pragma unroll
            for (int kb = 0; kb < 4; ++kb) {
                w2f[kb] = wfrag_f4(w2r + kb * 32);
                w3f[kb] = wfrag_f4(w3r + kb * 32);
            }
        }
        const float b2n = b2l[ncol];
        const float b3n = b3l[ncol];

        const int m2 = lane * 2;
        float psum = 0.0f;

        for (int c8 = 0; c8 < 8; ++c8) {
            const int j0 = c8 * 64;
            __syncthreads();

            // ---- build h1 chunk (64 x 128) as bf16 ----
            {
                const float am0 = amrow[m2],     am1 = amrow[m2 + 1];
                const float wd0 = wdsr[m2],      wd1 = wdsr[m2 + 1];
                #pragma unroll
                for (int rr = 0; rr < 8; ++rr) {
                    const int row = rr * 8 + w;
                    const int jg  = j0 + row;
                    const float2 bv = *(const float2*)&Bc[(size_t)jg * NH + m2];
                    const float d = distrow[jg];
                    const float v0 = fmaxf(am0 + bv.x + d * wd0, 0.0f);
                    const float v1 = fmaxf(am1 + bv.y + d * wd1, 0.0f);
                    const unsigned p = (unsigned)(unsigned short)f2bf(v0) |
                                       ((unsigned)(unsigned short)f2bf(v1) << 16);
                    *(unsigned*)&h1s[row * HSTR + m2] = p;
                }
            }
            __syncthreads();

            // ---- GEMM1: h2 = relu(h1 @ W2^T + b2) ----
            #pragma unroll
            for (int jt = 0; jt < 4; ++jt) {
                f32x4 acc = {0.f, 0.f, 0.f, 0.f};
                const short* arow = &h1s[(jt * 16 + c) * HSTR + q * 8];
                #pragma unroll
                for (int kb = 0; kb < 4; ++kb) {
                    bf16x8 a = *(const bf16x8*)(arow + kb * 32);
                    acc = __builtin_amdgcn_mfma_f32_16x16x32_bf16(a, w2f[kb], acc, 0, 0, 0);
                }
                #pragma unroll
                for (int r = 0; r < 4; ++r) {
                    const int row = jt * 16 + q * 4 + r;
                    h2s[row * HSTR + ncol] = f2bf(fmaxf(acc[r] + b2n, 0.0f));
                }
            }
            __syncthreads();

            // ---- GEMM2: diag-masked column sum of h2 @ W3^T + b3 ----
            #pragma unroll
            for (int jt = 0; jt < 4; ++jt) {
                f32x4 acc = {0.f, 0.f, 0.f, 0.f};
                const short* arow = &h2s[(jt * 16 + c) * HSTR + q * 8];
                #pragma unroll
                for (int kb = 0; kb < 4; ++kb) {
                    bf16x8 a = *(const bf16x8*)(arow + kb * 32);
                    acc = __builtin_amdgcn_mfma_f32_16x16x32_bf16(a, w3f[kb], acc, 0, 0, 0);
                }
                #pragma unroll
                for (int r = 0; r < 4; ++r) {
                    const int jg = j0 + jt * 16 + q * 4 + r;
                    if (jg != i) psum += acc[r] + b3n;
                }
            }
        }

        // ---- msum: reduce over quads (same ncol), into xs2 hi half ----
        psum += __shfl_xor(psum, 16, 64);
        psum += __shfl_xor(psum, 32, 64);
        if (lane < 16) xs2[NH + ncol] = psum;
        __syncthreads();

        // ---- tail: update MLP (fp32 GEMV, 4 lanes per output row) ----
        // L1: K=256
        {
            const float* wr = uW1l + (size_t)nn * 256 + ks * 4;
            float p = 0.f;
            #pragma unroll
            for (int it = 0; it < 16; ++it) {
                const float4 wv = *(const float4*)(wr + it * 16);
                const float4 xv = *(const float4*)&xs2[it * 16 + ks * 4];
                p += wv.x * xv.x + wv.y * xv.y + wv.z * xv.z + wv.w * xv.w;
            }
            part[ks * NH + nn] = p;
        }
        __syncthreads();
        if (t < NH)
            hx[t] = fmaxf(ub1l[t] + part[t] + part[NH + t] + part[2 * NH + t] + part[3 * NH + t], 0.f);
        __syncthreads();
        // L2: K=128
        {
            const float* wr = uW2l + (size_t)nn * NH + ks * 4;
            float p = 0.f;
            #pragma unroll
            for (int it = 0; it < 8; ++it) {
                const float4 wv = *(const float4*)(wr + it * 16);
                const float4 xv = *(const float4*)&hx[it * 16 + ks * 4];
                p += wv.x * xv.x + wv.y * xv.y + wv.z * xv.z + wv.w * xv.w;
            }
            part[ks * NH + nn] = p;
        }
        __syncthreads();
        if (t < NH)
            hy[t] = fmaxf(ub2l[t] + part[t] + part[NH + t] + part[2 * NH + t] + part[3 * NH + t], 0.f);
        __syncthreads();
        // L3: K=128, no relu
        {
            const float* wr = uW3l + (size_t)nn * NH + ks * 4;
            float p = 0.f;
            #pragma unroll
            for (int it = 0; it < 8; ++it) {
                const float4 wv = *(const float4*)(wr + it * 16);
                const float4 xv = *(const float4*)&hy[it * 16 + ks * 4];
                p += wv.x * xv.x + wv.y * xv.y + wv.z * xv.z + wv.w * xv.w;
            }
            part[ks * NH + nn] = p;
        }
        __syncthreads();
        if (t < NH) {
            const float v = ub3l[t] + part[t] + part[NH + t] + part[2 * NH + t] + part[3 * NH + t];
            if (l == 2) out[(size_t)i * NH + t] = v;
            hx[t] = v;   // new z
        }
        if (l < 2) {
            __syncthreads();
            // ab for next layer from new z (hx)
            {
                const float* pr = mW1 + (size_t)(l + 1) * 128 * 257 + (size_t)nn * 257;
                float pa = 0.f, pb = 0.f;
                #pragma unroll
                for (int it = 0; it < 8; ++it) {
                    #pragma unroll
                    for (int j = 0; j < 4; ++j) {
                        const int k = it * 16 + ks * 4 + j;
                        const float x = hx[k];
                        pa += x * pr[k];
                        pb += x * pr[NH + k];
                    }
                }
                part[ks * NH + nn] = pa;
                part2[ks * NH + nn] = pb;
            }
            __syncthreads();
            if (t < NH) {
                arow_s[t] = part[t] + part[NH + t] + part[2 * NH + t] + part[3 * NH + t];
                Bn[(size_t)i * NH + t] = part2[t] + part2[NH + t] + part2[2 * NH + t] + part2[3 * NH + t];
                xs2[t] = hx[t];   // z for next layer's tail
            }
            gsync(sync_ws, 1 + l);
        }
    }
}

// ---------------------------------------------------------------- host ------
extern "C" void kernel_launch(void* const* d_in, const int* in_sizes, int n_in,
                              void* d_out, int out_size, void* d_ws, size_t ws_size,
                              hipStream_t stream) {
    fp32p obs   = (fp32p)d_in[0];
    fp32p pos   = (fp32p)d_in[1];
    fp32p encW1 = (fp32p)d_in[2];  fp32p encb1 = (fp32p)d_in[3];
    fp32p encW2 = (fp32p)d_in[4];  fp32p encb2 = (fp32p)d_in[5];
    fp32p encW3 = (fp32p)d_in[6];  fp32p encb3 = (fp32p)d_in[7];
    fp32p msgW1 = (fp32p)d_in[8];  fp32p msgb1 = (fp32p)d_in[9];
    fp32p msgW2 = (fp32p)d_in[10]; fp32p msgb2 = (fp32p)d_in[11];
    fp32p msgW3 = (fp32p)d_in[12]; fp32p msgb3 = (fp32p)d_in[13];
    fp32p updW1 = (fp32p)d_in[14]; fp32p updb1 = (fp32p)d_in[15];
    fp32p updW2 = (fp32p)d_in[16]; fp32p updb2 = (fp32p)d_in[17];
    fp32p updW3 = (fp32p)d_in[18]; fp32p updb3 = (fp32p)d_in[19];

    float* ws = (float*)d_ws;
    float* B0 = ws;
    float* B1 = B0 + NA * NH;
    unsigned* sync_ws = (unsigned*)(B1 + NA * NH);

    init_kernel<<<1, 1024, 0, stream>>>(sync_ws);
    gnn_kernel<<<NA, 512, 0, stream>>>(
        obs, pos,
        encW1, encb1, encW2, encb2, encW3, encb3,
        msgW1, msgb1, msgW2, msgb2, msgW3, msgb3,
        updW1, updb1, updW2, updb2, updW3, updb3,
        (float*)d_out, B0, B1, sync_ws);
}